// Round 1
// baseline (4243.925 us; speedup 1.0000x reference)
//
#include <hip/hip_runtime.h>
#include <math.h>

static constexpr int N = 50000;
static constexpr int E = 800000;
static constexpr int D = 128;      // D_IN = D_HID
static constexpr int DO = 64;      // D_OUT

// ---------------- degree / norm precompute ----------------

__global__ __launch_bounds__(256) void k_init_deg(float* __restrict__ deg) {
  int i = blockIdx.x * 256 + threadIdx.x;
  if (i < N) deg[i] = 1.0f;                       // +1 self-loop
}

__global__ __launch_bounds__(256) void k_scatter_deg(const int* __restrict__ dst,
                                                     const float* __restrict__ ew,
                                                     float* __restrict__ deg) {
  int e = blockIdx.x * 256 + threadIdx.x;
  if (e < E)
    __hip_atomic_fetch_add(&deg[dst[e]], ew[e], __ATOMIC_RELAXED, __HIP_MEMORY_SCOPE_AGENT);
}

__global__ __launch_bounds__(256) void k_finalize_dinv(float* __restrict__ dinv) {
  int i = blockIdx.x * 256 + threadIdx.x;
  if (i < N) dinv[i] = 1.0f / sqrtf(dinv[i]);     // deg >= 1 always
}

__global__ __launch_bounds__(256) void k_norm(const int* __restrict__ src,
                                              const int* __restrict__ dst,
                                              const float* __restrict__ ew,
                                              const float* __restrict__ dinv,
                                              float* __restrict__ norm) {
  int e = blockIdx.x * 256 + threadIdx.x;
  if (e < E) norm[e] = dinv[src[e]] * ew[e] * dinv[dst[e]];
}

// ---------------- aggregation A(h) = scatter(h[src]*norm -> dst) + h*dinv^2 ----------------

// init out with the self-loop term: out[i][:] = h[i][:] * dinv[i]^2
__global__ __launch_bounds__(256) void k_self_init(const float* __restrict__ h,
                                                   const float* __restrict__ dinv,
                                                   float* __restrict__ out) {
  int g = blockIdx.x * 256 + threadIdx.x;         // over N*32 float4's
  int node = g >> 5;
  if (node >= N) return;
  float s = dinv[node];
  s *= s;
  float4 v = ((const float4*)h)[g];
  v.x *= s; v.y *= s; v.z *= s; v.w *= s;
  ((float4*)out)[g] = v;
}

// 32 threads per edge, each handles 4 consecutive floats
__global__ __launch_bounds__(256) void k_edge_scatter(const float* __restrict__ h,
                                                      const int* __restrict__ src,
                                                      const int* __restrict__ dst,
                                                      const float* __restrict__ norm,
                                                      float* __restrict__ out) {
  long long g = (long long)blockIdx.x * 256 + threadIdx.x;  // E*32 threads
  int e = (int)(g >> 5);
  int q = (int)(g & 31);
  if (e >= E) return;
  int s = src[e];
  int d = dst[e];
  float w = norm[e];
  float4 v = ((const float4*)(h + (size_t)s * D))[q];
  float* o = out + (size_t)d * D + q * 4;
  __hip_atomic_fetch_add(o + 0, v.x * w, __ATOMIC_RELAXED, __HIP_MEMORY_SCOPE_AGENT);
  __hip_atomic_fetch_add(o + 1, v.y * w, __ATOMIC_RELAXED, __HIP_MEMORY_SCOPE_AGENT);
  __hip_atomic_fetch_add(o + 2, v.z * w, __ATOMIC_RELAXED, __HIP_MEMORY_SCOPE_AGENT);
  __hip_atomic_fetch_add(o + 3, v.w * w, __ATOMIC_RELAXED, __HIP_MEMORY_SCOPE_AGENT);
}

// ---------------- GEMM: out[N,128] = A[N,128] @ W[128,128] + bias (opt relu) ----------------

template <bool RELU>
__global__ __launch_bounds__(256) void k_gemm_bias(const float* __restrict__ A,
                                                   const float* __restrict__ W,
                                                   const float* __restrict__ bias,
                                                   float* __restrict__ out) {
  __shared__ __align__(16) float Wl[128][128];   // 64 KB
  __shared__ __align__(16) float Al[16][132];    // padded rows (132*4B = 33*16B)
  const int tid = threadIdx.x;

  {  // load W (16384 floats = 4096 float4)
    const float4* W4 = (const float4*)W;
    float4* Wl4 = (float4*)&Wl[0][0];
#pragma unroll
    for (int i = 0; i < 16; ++i) Wl4[tid + i * 256] = W4[tid + i * 256];
  }
  const int row0 = blockIdx.x * 16;
  {  // load A tile (16x128 = 512 float4)
    const float4* A4 = (const float4*)(A + (size_t)row0 * D);
#pragma unroll
    for (int i = 0; i < 2; ++i) {
      int idx = tid + i * 256;
      int r = idx >> 5, c4 = idx & 31;
      *(float4*)&Al[r][c4 * 4] = A4[idx];
    }
  }
  __syncthreads();

  const int c = tid & 127;
  const int rbase = (tid >> 7) * 8;
  float acc[8] = {0.f, 0.f, 0.f, 0.f, 0.f, 0.f, 0.f, 0.f};
  for (int k4 = 0; k4 < 32; ++k4) {
    float w0 = Wl[4 * k4 + 0][c];
    float w1 = Wl[4 * k4 + 1][c];
    float w2 = Wl[4 * k4 + 2][c];
    float w3 = Wl[4 * k4 + 3][c];
#pragma unroll
    for (int r = 0; r < 8; ++r) {
      float4 a = *(const float4*)&Al[rbase + r][4 * k4];
      acc[r] = fmaf(a.x, w0, acc[r]);
      acc[r] = fmaf(a.y, w1, acc[r]);
      acc[r] = fmaf(a.z, w2, acc[r]);
      acc[r] = fmaf(a.w, w3, acc[r]);
    }
  }
  const float b = bias[c];
#pragma unroll
  for (int r = 0; r < 8; ++r) {
    float v = acc[r] + b;
    if (RELU) v = fmaxf(v, 0.f);
    out[(size_t)(row0 + rbase + r) * D + c] = v;
  }
}

// final heads: mu = A@Wmu+bmu, std = A@Wstd+bstd  (Wmu/Wstd are [128,64])
__global__ __launch_bounds__(256) void k_gemm_dual(const float* __restrict__ A,
                                                   const float* __restrict__ Wmu,
                                                   const float* __restrict__ Wstd,
                                                   const float* __restrict__ bmu,
                                                   const float* __restrict__ bstd,
                                                   float* __restrict__ out) {
  __shared__ __align__(16) float Wl[128][128];   // [k][c<64: mu, c>=64: std]
  __shared__ __align__(16) float Al[16][132];
  const int tid = threadIdx.x;

  {  // each weight: 8192 floats = 2048 float4
    const float4* Wm4 = (const float4*)Wmu;
    const float4* Ws4 = (const float4*)Wstd;
#pragma unroll
    for (int i = 0; i < 8; ++i) {
      int idx = tid + i * 256;     // float4 index
      int k = idx >> 4;            // 16 float4 per 64-wide row
      int c4 = idx & 15;
      *(float4*)&Wl[k][c4 * 4] = Wm4[idx];
      *(float4*)&Wl[k][64 + c4 * 4] = Ws4[idx];
    }
  }
  const int row0 = blockIdx.x * 16;
  {
    const float4* A4 = (const float4*)(A + (size_t)row0 * D);
#pragma unroll
    for (int i = 0; i < 2; ++i) {
      int idx = tid + i * 256;
      int r = idx >> 5, c4 = idx & 31;
      *(float4*)&Al[r][c4 * 4] = A4[idx];
    }
  }
  __syncthreads();

  const int c = tid & 127;
  const int rbase = (tid >> 7) * 8;
  float acc[8] = {0.f, 0.f, 0.f, 0.f, 0.f, 0.f, 0.f, 0.f};
  for (int k4 = 0; k4 < 32; ++k4) {
    float w0 = Wl[4 * k4 + 0][c];
    float w1 = Wl[4 * k4 + 1][c];
    float w2 = Wl[4 * k4 + 2][c];
    float w3 = Wl[4 * k4 + 3][c];
#pragma unroll
    for (int r = 0; r < 8; ++r) {
      float4 a = *(const float4*)&Al[rbase + r][4 * k4];
      acc[r] = fmaf(a.x, w0, acc[r]);
      acc[r] = fmaf(a.y, w1, acc[r]);
      acc[r] = fmaf(a.z, w2, acc[r]);
      acc[r] = fmaf(a.w, w3, acc[r]);
    }
  }
  const bool is_mu = (c < DO);
  const int cc = is_mu ? c : (c - DO);
  const float b = is_mu ? bmu[cc] : bstd[cc];
  float* base = is_mu ? out : (out + (size_t)N * DO);
#pragma unroll
  for (int r = 0; r < 8; ++r) {
    base[(size_t)(row0 + rbase + r) * DO + cc] = acc[r] + b;
  }
}

// ---------------- launcher ----------------

extern "C" void kernel_launch(void* const* d_in, const int* in_sizes, int n_in,
                              void* d_out, int out_size, void* d_ws, size_t ws_size,
                              hipStream_t stream) {
  const float* x    = (const float*)d_in[0];
  const int*   ei   = (const int*)d_in[1];     // [2, E] int32
  const float* ew   = (const float*)d_in[2];
  const float* W1   = (const float*)d_in[3];
  const float* b1   = (const float*)d_in[4];
  const float* W2   = (const float*)d_in[5];
  const float* b2   = (const float*)d_in[6];
  const float* Wmu  = (const float*)d_in[7];
  const float* bmu  = (const float*)d_in[8];
  const float* Wstd = (const float*)d_in[9];
  const float* bstd = (const float*)d_in[10];
  float* out = (float*)d_out;

  const int* srcI = ei;
  const int* dstI = ei + E;

  float* ws   = (float*)d_ws;
  float* dinv = ws;                        // N floats
  float* norm = ws + N;                    // E floats
  float* buf0 = ws + N + E;                // N*D floats (aggregation result)
  float* buf1 = buf0 + (size_t)N * D;      // N*D floats (post-GEMM h)

  dim3 blk(256);
  const int gN  = (N + 255) / 256;
  const int gE  = (E + 255) / 256;
  const int gSelf = (N * 32 + 255) / 256;          // N*32 threads (float4 per thread)
  const int gEdge = (int)(((long long)E * 32 + 255) / 256);
  const int gGemm = N / 16;                        // 50000/16 = 3125 exactly

  // degree -> dinv -> per-edge norm (shared by all 3 aggregation passes)
  k_init_deg<<<gN, blk, 0, stream>>>(dinv);
  k_scatter_deg<<<gE, blk, 0, stream>>>(dstI, ew, dinv);
  k_finalize_dinv<<<gN, blk, 0, stream>>>(dinv);
  k_norm<<<gE, blk, 0, stream>>>(srcI, dstI, ew, dinv, norm);

  // layer 1: h1 = relu(A(x) @ W1 + b1)
  k_self_init<<<gSelf, blk, 0, stream>>>(x, dinv, buf0);
  k_edge_scatter<<<gEdge, blk, 0, stream>>>(x, srcI, dstI, norm, buf0);
  k_gemm_bias<true><<<gGemm, blk, 0, stream>>>(buf0, W1, b1, buf1);

  // layer 2: h2 = relu(A(h1) @ W2 + b2)
  k_self_init<<<gSelf, blk, 0, stream>>>(buf1, dinv, buf0);
  k_edge_scatter<<<gEdge, blk, 0, stream>>>(buf1, srcI, dstI, norm, buf0);
  k_gemm_bias<true><<<gGemm, blk, 0, stream>>>(buf0, W2, b2, buf1);

  // heads: one shared aggregation, two output projections
  k_self_init<<<gSelf, blk, 0, stream>>>(buf1, dinv, buf0);
  k_edge_scatter<<<gEdge, blk, 0, stream>>>(buf1, srcI, dstI, norm, buf0);
  k_gemm_dual<<<gGemm, blk, 0, stream>>>(buf0, Wmu, Wstd, bmu, bstd, out);
}

// Round 2
// 653.181 us; speedup vs baseline: 6.4973x; 6.4973x over previous
//
#include <hip/hip_runtime.h>
#include <math.h>

static constexpr int N = 50000;
static constexpr int E = 800000;
static constexpr int D = 128;      // D_IN = D_HID
static constexpr int DO = 64;      // D_OUT

// ---------------- CSR build + degree/norm precompute ----------------

// rowptr[0..N] used as count buffer first; dinv starts at 1.0 (self-loop)
__global__ __launch_bounds__(256) void k_init(float* __restrict__ dinv,
                                              int* __restrict__ cnt) {
  int i = blockIdx.x * 256 + threadIdx.x;
  if (i < N) { dinv[i] = 1.0f; cnt[i] = 0; }
  if (i == N) cnt[N] = 0;
}

// histogram of dst + weighted degree in one pass
__global__ __launch_bounds__(256) void k_hist(const int* __restrict__ dst,
                                              const float* __restrict__ ew,
                                              float* __restrict__ deg,
                                              int* __restrict__ cnt) {
  int e = blockIdx.x * 256 + threadIdx.x;
  if (e < E) {
    int d = dst[e];
    __hip_atomic_fetch_add(&deg[d], ew[e], __ATOMIC_RELAXED, __HIP_MEMORY_SCOPE_AGENT);
    __hip_atomic_fetch_add(&cnt[d], 1, __ATOMIC_RELAXED, __HIP_MEMORY_SCOPE_AGENT);
  }
}

__global__ __launch_bounds__(256) void k_finalize_dinv(float* __restrict__ dinv) {
  int i = blockIdx.x * 256 + threadIdx.x;
  if (i < N) dinv[i] = 1.0f / sqrtf(dinv[i]);     // deg >= 1 always
}

// single-block exclusive scan of cnt (in rowptr) -> rowptr & cursor
__global__ __launch_bounds__(1024) void k_scan(int* __restrict__ rowptr,
                                               int* __restrict__ cursor) {
  __shared__ int sm[1024];
  __shared__ int carry;
  const int tid = threadIdx.x;
  if (tid == 0) carry = 0;
  __syncthreads();
  for (int base = 0; base < N; base += 1024) {
    int i = base + tid;
    int v = (i < N) ? rowptr[i] : 0;
    sm[tid] = v;
    __syncthreads();
#pragma unroll
    for (int off = 1; off < 1024; off <<= 1) {
      int t = (tid >= off) ? sm[tid - off] : 0;
      __syncthreads();
      sm[tid] += t;
      __syncthreads();
    }
    int excl = sm[tid] - v + carry;
    if (i < N) { rowptr[i] = excl; cursor[i] = excl; }
    __syncthreads();
    if (tid == 0) carry += sm[1023];
    __syncthreads();
  }
  if (tid == 0) rowptr[N] = carry;   // == E
}

// scatter edges into CSR order; compute norm inline
__global__ __launch_bounds__(256) void k_build_csr(const int* __restrict__ src,
                                                   const int* __restrict__ dst,
                                                   const float* __restrict__ ew,
                                                   const float* __restrict__ dinv,
                                                   int* __restrict__ cursor,
                                                   int* __restrict__ csr_src,
                                                   float* __restrict__ csr_w) {
  int e = blockIdx.x * 256 + threadIdx.x;
  if (e >= E) return;
  int s = src[e], d = dst[e];
  float w = dinv[s] * ew[e] * dinv[d];
  int pos = __hip_atomic_fetch_add(&cursor[d], 1, __ATOMIC_RELAXED, __HIP_MEMORY_SCOPE_AGENT);
  csr_src[pos] = s;
  csr_w[pos] = w;
}

// ---------------- aggregation: out[i] = sum_{e->i} h[src]*w + h[i]*dinv[i]^2 ----------------
// one 64-lane wave per node; lane owns float2 of the 128-dim row
__global__ __launch_bounds__(256) void k_aggregate(const float* __restrict__ h,
                                                   const int* __restrict__ rowptr,
                                                   const int* __restrict__ csr_src,
                                                   const float* __restrict__ csr_w,
                                                   const float* __restrict__ dinv,
                                                   float* __restrict__ out) {
  int node = blockIdx.x * 4 + (threadIdx.x >> 6);
  if (node >= N) return;
  int lane = threadIdx.x & 63;

  float s = dinv[node];
  float s2 = s * s;
  float2 hv = *(const float2*)(h + (size_t)node * D + lane * 2);
  float accx = hv.x * s2, accy = hv.y * s2;

  int beg = rowptr[node];
  int end = rowptr[node + 1];
  for (int e = beg; e < end; ++e) {
    int sidx = csr_src[e];          // wave-uniform
    float w = csr_w[e];             // wave-uniform
    float2 v = *(const float2*)(h + (size_t)sidx * D + lane * 2);
    accx = fmaf(v.x, w, accx);
    accy = fmaf(v.y, w, accy);
  }
  float2 r; r.x = accx; r.y = accy;
  *(float2*)(out + (size_t)node * D + lane * 2) = r;
}

// ---------------- GEMM: out[N,128] = A[N,128] @ W[128,128] + bias (opt relu) ----------------

template <bool RELU>
__global__ __launch_bounds__(256) void k_gemm_bias(const float* __restrict__ A,
                                                   const float* __restrict__ W,
                                                   const float* __restrict__ bias,
                                                   float* __restrict__ out) {
  __shared__ __align__(16) float Wl[128][128];   // 64 KB
  __shared__ __align__(16) float Al[16][132];    // padded rows
  const int tid = threadIdx.x;

  {  // load W (4096 float4)
    const float4* W4 = (const float4*)W;
    float4* Wl4 = (float4*)&Wl[0][0];
#pragma unroll
    for (int i = 0; i < 16; ++i) Wl4[tid + i * 256] = W4[tid + i * 256];
  }
  const int row0 = blockIdx.x * 16;
  {  // load A tile (512 float4)
    const float4* A4 = (const float4*)(A + (size_t)row0 * D);
#pragma unroll
    for (int i = 0; i < 2; ++i) {
      int idx = tid + i * 256;
      int r = idx >> 5, c4 = idx & 31;
      *(float4*)&Al[r][c4 * 4] = A4[idx];
    }
  }
  __syncthreads();

  const int c = tid & 127;
  const int rbase = (tid >> 7) * 8;
  float acc[8] = {0.f, 0.f, 0.f, 0.f, 0.f, 0.f, 0.f, 0.f};
  for (int k4 = 0; k4 < 32; ++k4) {
    float w0 = Wl[4 * k4 + 0][c];
    float w1 = Wl[4 * k4 + 1][c];
    float w2 = Wl[4 * k4 + 2][c];
    float w3 = Wl[4 * k4 + 3][c];
#pragma unroll
    for (int r = 0; r < 8; ++r) {
      float4 a = *(const float4*)&Al[rbase + r][4 * k4];
      acc[r] = fmaf(a.x, w0, acc[r]);
      acc[r] = fmaf(a.y, w1, acc[r]);
      acc[r] = fmaf(a.z, w2, acc[r]);
      acc[r] = fmaf(a.w, w3, acc[r]);
    }
  }
  const float b = bias[c];
#pragma unroll
  for (int r = 0; r < 8; ++r) {
    float v = acc[r] + b;
    if (RELU) v = fmaxf(v, 0.f);
    out[(size_t)(row0 + rbase + r) * D + c] = v;
  }
}

// final heads: mu = A@Wmu+bmu, std = A@Wstd+bstd  (Wmu/Wstd are [128,64])
__global__ __launch_bounds__(256) void k_gemm_dual(const float* __restrict__ A,
                                                   const float* __restrict__ Wmu,
                                                   const float* __restrict__ Wstd,
                                                   const float* __restrict__ bmu,
                                                   const float* __restrict__ bstd,
                                                   float* __restrict__ out) {
  __shared__ __align__(16) float Wl[128][128];   // [k][c<64: mu, c>=64: std]
  __shared__ __align__(16) float Al[16][132];
  const int tid = threadIdx.x;

  {
    const float4* Wm4 = (const float4*)Wmu;
    const float4* Ws4 = (const float4*)Wstd;
#pragma unroll
    for (int i = 0; i < 8; ++i) {
      int idx = tid + i * 256;
      int k = idx >> 4;
      int c4 = idx & 15;
      *(float4*)&Wl[k][c4 * 4] = Wm4[idx];
      *(float4*)&Wl[k][64 + c4 * 4] = Ws4[idx];
    }
  }
  const int row0 = blockIdx.x * 16;
  {
    const float4* A4 = (const float4*)(A + (size_t)row0 * D);
#pragma unroll
    for (int i = 0; i < 2; ++i) {
      int idx = tid + i * 256;
      int r = idx >> 5, c4 = idx & 31;
      *(float4*)&Al[r][c4 * 4] = A4[idx];
    }
  }
  __syncthreads();

  const int c = tid & 127;
  const int rbase = (tid >> 7) * 8;
  float acc[8] = {0.f, 0.f, 0.f, 0.f, 0.f, 0.f, 0.f, 0.f};
  for (int k4 = 0; k4 < 32; ++k4) {
    float w0 = Wl[4 * k4 + 0][c];
    float w1 = Wl[4 * k4 + 1][c];
    float w2 = Wl[4 * k4 + 2][c];
    float w3 = Wl[4 * k4 + 3][c];
#pragma unroll
    for (int r = 0; r < 8; ++r) {
      float4 a = *(const float4*)&Al[rbase + r][4 * k4];
      acc[r] = fmaf(a.x, w0, acc[r]);
      acc[r] = fmaf(a.y, w1, acc[r]);
      acc[r] = fmaf(a.z, w2, acc[r]);
      acc[r] = fmaf(a.w, w3, acc[r]);
    }
  }
  const bool is_mu = (c < DO);
  const int cc = is_mu ? c : (c - DO);
  const float b = is_mu ? bmu[cc] : bstd[cc];
  float* base = is_mu ? out : (out + (size_t)N * DO);
#pragma unroll
  for (int r = 0; r < 8; ++r) {
    base[(size_t)(row0 + rbase + r) * DO + cc] = acc[r] + b;
  }
}

// ---------------- launcher ----------------

extern "C" void kernel_launch(void* const* d_in, const int* in_sizes, int n_in,
                              void* d_out, int out_size, void* d_ws, size_t ws_size,
                              hipStream_t stream) {
  const float* x    = (const float*)d_in[0];
  const int*   ei   = (const int*)d_in[1];     // [2, E] int32
  const float* ew   = (const float*)d_in[2];
  const float* W1   = (const float*)d_in[3];
  const float* b1   = (const float*)d_in[4];
  const float* W2   = (const float*)d_in[5];
  const float* b2   = (const float*)d_in[6];
  const float* Wmu  = (const float*)d_in[7];
  const float* bmu  = (const float*)d_in[8];
  const float* Wstd = (const float*)d_in[9];
  const float* bstd = (const float*)d_in[10];
  float* out = (float*)d_out;

  const int* srcI = ei;
  const int* dstI = ei + E;

  char* p = (char*)d_ws;
  float* dinv    = (float*)p;  p += (size_t)N * 4;
  int*   rowptr  = (int*)p;    p += (size_t)(N + 1) * 4;
  int*   cursor  = (int*)p;    p += (size_t)N * 4;
  int*   csr_src = (int*)p;    p += (size_t)E * 4;
  float* csr_w   = (float*)p;  p += (size_t)E * 4;
  float* buf0    = (float*)p;  p += (size_t)N * D * 4;   // aggregation result
  float* buf1    = (float*)p;                            // post-GEMM h

  dim3 blk(256);
  const int gN  = (N + 256) / 256;   // covers i==N for cnt[N]
  const int gE  = (E + 255) / 256;
  const int gAgg = (N + 3) / 4;
  const int gGemm = N / 16;          // 3125 exactly

  // CSR + norm precompute (once per call)
  k_init<<<gN, blk, 0, stream>>>(dinv, rowptr);
  k_hist<<<gE, blk, 0, stream>>>(dstI, ew, dinv, rowptr);
  k_finalize_dinv<<<gN, blk, 0, stream>>>(dinv);
  k_scan<<<1, 1024, 0, stream>>>(rowptr, cursor);
  k_build_csr<<<gE, blk, 0, stream>>>(srcI, dstI, ew, dinv, cursor, csr_src, csr_w);

  // layer 1: h1 = relu(A(x) @ W1 + b1)
  k_aggregate<<<gAgg, blk, 0, stream>>>(x, rowptr, csr_src, csr_w, dinv, buf0);
  k_gemm_bias<true><<<gGemm, blk, 0, stream>>>(buf0, W1, b1, buf1);

  // layer 2: h2 = relu(A(h1) @ W2 + b2)
  k_aggregate<<<gAgg, blk, 0, stream>>>(buf1, rowptr, csr_src, csr_w, dinv, buf0);
  k_gemm_bias<true><<<gGemm, blk, 0, stream>>>(buf0, W2, b2, buf1);

  // heads: one shared aggregation, two output projections
  k_aggregate<<<gAgg, blk, 0, stream>>>(buf1, rowptr, csr_src, csr_w, dinv, buf0);
  k_gemm_dual<<<gGemm, blk, 0, stream>>>(buf0, Wmu, Wstd, bmu, bstd, out);
}

// Round 3
// 441.158 us; speedup vs baseline: 9.6200x; 1.4806x over previous
//
#include <hip/hip_runtime.h>
#include <math.h>

static constexpr int N = 50000;
static constexpr int E = 800000;
static constexpr int D = 128;      // D_IN = D_HID
static constexpr int DO = 64;      // D_OUT
static constexpr int NB = (N + 255) / 256;   // 196 scan blocks

// ---------------- CSR build + degree/norm precompute ----------------

__global__ __launch_bounds__(256) void k_init(float* __restrict__ dinv,
                                              int* __restrict__ cnt) {
  int i = blockIdx.x * 256 + threadIdx.x;
  if (i < N) { dinv[i] = 1.0f; cnt[i] = 0; }
}

__global__ __launch_bounds__(256) void k_hist(const int* __restrict__ dst,
                                              const float* __restrict__ ew,
                                              float* __restrict__ deg,
                                              int* __restrict__ cnt) {
  int e = blockIdx.x * 256 + threadIdx.x;
  if (e < E) {
    int d = dst[e];
    __hip_atomic_fetch_add(&deg[d], ew[e], __ATOMIC_RELAXED, __HIP_MEMORY_SCOPE_AGENT);
    __hip_atomic_fetch_add(&cnt[d], 1, __ATOMIC_RELAXED, __HIP_MEMORY_SCOPE_AGENT);
  }
}

__global__ __launch_bounds__(256) void k_finalize_dinv(float* __restrict__ dinv) {
  int i = blockIdx.x * 256 + threadIdx.x;
  if (i < N) dinv[i] = 1.0f / sqrtf(dinv[i]);     // deg >= 1 always
}

// hierarchical scan: S1 block sums -> S2 scan partials -> S3 local scan + offset
__global__ __launch_bounds__(256) void k_scan1(const int* __restrict__ cnt,
                                               int* __restrict__ partial) {
  __shared__ int sm[256];
  int i = blockIdx.x * 256 + threadIdx.x;
  int t = threadIdx.x;
  sm[t] = (i < N) ? cnt[i] : 0;
  __syncthreads();
#pragma unroll
  for (int off = 128; off > 0; off >>= 1) {
    if (t < off) sm[t] += sm[t + off];
    __syncthreads();
  }
  if (t == 0) partial[blockIdx.x] = sm[0];
}

__global__ __launch_bounds__(256) void k_scan2(int* __restrict__ partial) {
  __shared__ int sm[256];
  int t = threadIdx.x;
  int v = (t < NB) ? partial[t] : 0;
  sm[t] = v;
  __syncthreads();
#pragma unroll
  for (int off = 1; off < 256; off <<= 1) {
    int u = (t >= off) ? sm[t - off] : 0;
    __syncthreads();
    sm[t] += u;
    __syncthreads();
  }
  if (t < NB) partial[t] = sm[t] - v;   // exclusive block offsets
}

__global__ __launch_bounds__(256) void k_scan3(const int* __restrict__ cnt,
                                               const int* __restrict__ partial,
                                               int* __restrict__ rowptr,
                                               int* __restrict__ cursor) {
  __shared__ int sm[256];
  int i = blockIdx.x * 256 + threadIdx.x;
  int t = threadIdx.x;
  int v = (i < N) ? cnt[i] : 0;
  sm[t] = v;
  __syncthreads();
#pragma unroll
  for (int off = 1; off < 256; off <<= 1) {
    int u = (t >= off) ? sm[t - off] : 0;
    __syncthreads();
    sm[t] += u;
    __syncthreads();
  }
  int excl = sm[t] - v + partial[blockIdx.x];
  if (i < N) { rowptr[i] = excl; cursor[i] = excl; }
  if (i == N) rowptr[N] = E;
}

__global__ __launch_bounds__(256) void k_build_csr(const int* __restrict__ src,
                                                   const int* __restrict__ dst,
                                                   const float* __restrict__ ew,
                                                   const float* __restrict__ dinv,
                                                   int* __restrict__ cursor,
                                                   int* __restrict__ csr_src,
                                                   float* __restrict__ csr_w) {
  int e = blockIdx.x * 256 + threadIdx.x;
  if (e >= E) return;
  int s = src[e], d = dst[e];
  float w = dinv[s] * ew[e] * dinv[d];
  int pos = __hip_atomic_fetch_add(&cursor[d], 1, __ATOMIC_RELAXED, __HIP_MEMORY_SCOPE_AGENT);
  csr_src[pos] = s;
  csr_w[pos] = w;
}

// ---------------- aggregation: out[i] = sum_{e->i} h[src]*w + h[i]*dinv[i]^2 ----------------
// one 64-lane wave per node; lane owns float2 of the 128-dim row; 4x edge unroll for MLP
__global__ __launch_bounds__(256) void k_aggregate(const float* __restrict__ h,
                                                   const int* __restrict__ rowptr,
                                                   const int* __restrict__ csr_src,
                                                   const float* __restrict__ csr_w,
                                                   const float* __restrict__ dinv,
                                                   float* __restrict__ out) {
  int node = blockIdx.x * 4 + (threadIdx.x >> 6);
  if (node >= N) return;
  int lane = threadIdx.x & 63;
  const float* hp = h + (size_t)lane * 2;

  float s = dinv[node];
  float s2 = s * s;
  float2 hv = *(const float2*)(hp + (size_t)node * D);
  float accx = hv.x * s2, accy = hv.y * s2;

  int beg = rowptr[node];
  int end = rowptr[node + 1];
  int e = beg;
  for (; e + 4 <= end; e += 4) {
    int i0 = csr_src[e + 0], i1 = csr_src[e + 1], i2 = csr_src[e + 2], i3 = csr_src[e + 3];
    float w0 = csr_w[e + 0], w1 = csr_w[e + 1], w2 = csr_w[e + 2], w3 = csr_w[e + 3];
    float2 v0 = *(const float2*)(hp + (size_t)i0 * D);
    float2 v1 = *(const float2*)(hp + (size_t)i1 * D);
    float2 v2 = *(const float2*)(hp + (size_t)i2 * D);
    float2 v3 = *(const float2*)(hp + (size_t)i3 * D);
    accx = fmaf(v0.x, w0, accx); accy = fmaf(v0.y, w0, accy);
    accx = fmaf(v1.x, w1, accx); accy = fmaf(v1.y, w1, accy);
    accx = fmaf(v2.x, w2, accx); accy = fmaf(v2.y, w2, accy);
    accx = fmaf(v3.x, w3, accx); accy = fmaf(v3.y, w3, accy);
  }
  for (; e < end; ++e) {
    int i0 = csr_src[e];
    float w0 = csr_w[e];
    float2 v0 = *(const float2*)(hp + (size_t)i0 * D);
    accx = fmaf(v0.x, w0, accx); accy = fmaf(v0.y, w0, accy);
  }
  float2 r; r.x = accx; r.y = accy;
  *(float2*)(out + (size_t)node * D + lane * 2) = r;
}

// ---------------- GEMM: out[N,128] = A[N,128] @ W[128,128] + bias (opt relu) ----------------
// block: 32 rows x 128 cols; thread: 4 rows x 4 cols (FMA-bound)

template <bool RELU>
__global__ __launch_bounds__(256) void k_gemm_bias(const float* __restrict__ A,
                                                   const float* __restrict__ W,
                                                   const float* __restrict__ bias,
                                                   float* __restrict__ out) {
  __shared__ __align__(16) float Wl[128][128];   // 64 KB
  __shared__ __align__(16) float Al[32][128];    // 16 KB
  const int tid = threadIdx.x;

  {  // load W (4096 float4)
    const float4* W4 = (const float4*)W;
    float4* Wl4 = (float4*)&Wl[0][0];
#pragma unroll
    for (int i = 0; i < 16; ++i) Wl4[tid + i * 256] = W4[tid + i * 256];
  }
  const int row0 = blockIdx.x * 32;
  {  // load A tile (1024 float4), guard tail rows
    const float4* A4 = (const float4*)(A + (size_t)row0 * D);
    float4* Al4 = (float4*)&Al[0][0];
#pragma unroll
    for (int i = 0; i < 4; ++i) {
      int idx = tid + i * 256;
      int r = idx >> 5;
      float4 v = make_float4(0.f, 0.f, 0.f, 0.f);
      if (row0 + r < N) v = A4[idx];
      Al4[idx] = v;
    }
  }
  __syncthreads();

  const int c0 = (tid & 31) * 4;
  const int r0 = (tid >> 5) * 4;
  float acc[4][4] = {};
  for (int k4 = 0; k4 < 32; ++k4) {
    float4 a[4];
#pragma unroll
    for (int r = 0; r < 4; ++r) a[r] = *(const float4*)&Al[r0 + r][k4 * 4];
    float4 w[4];
#pragma unroll
    for (int kk = 0; kk < 4; ++kk) w[kk] = *(const float4*)&Wl[k4 * 4 + kk][c0];
#pragma unroll
    for (int r = 0; r < 4; ++r) {
      float av0 = a[r].x, av1 = a[r].y, av2 = a[r].z, av3 = a[r].w;
#pragma unroll
      for (int cc = 0; cc < 4; ++cc) {
        float wv0 = (&w[0].x)[cc], wv1 = (&w[1].x)[cc], wv2 = (&w[2].x)[cc], wv3 = (&w[3].x)[cc];
        float v = acc[r][cc];
        v = fmaf(av0, wv0, v);
        v = fmaf(av1, wv1, v);
        v = fmaf(av2, wv2, v);
        v = fmaf(av3, wv3, v);
        acc[r][cc] = v;
      }
    }
  }
  float4 b = *(const float4*)&bias[c0];
#pragma unroll
  for (int r = 0; r < 4; ++r) {
    int row = row0 + r0 + r;
    if (row < N) {
      float4 v;
      v.x = acc[r][0] + b.x; v.y = acc[r][1] + b.y;
      v.z = acc[r][2] + b.z; v.w = acc[r][3] + b.w;
      if (RELU) {
        v.x = fmaxf(v.x, 0.f); v.y = fmaxf(v.y, 0.f);
        v.z = fmaxf(v.z, 0.f); v.w = fmaxf(v.w, 0.f);
      }
      *(float4*)&out[(size_t)row * D + c0] = v;
    }
  }
}

// heads: cols 0-63 -> mu = A@Wmu+bmu, cols 64-127 -> std = A@Wstd+bstd
__global__ __launch_bounds__(256) void k_gemm_dual(const float* __restrict__ A,
                                                   const float* __restrict__ Wmu,
                                                   const float* __restrict__ Wstd,
                                                   const float* __restrict__ bmu,
                                                   const float* __restrict__ bstd,
                                                   float* __restrict__ out) {
  __shared__ __align__(16) float Wl[128][128];
  __shared__ __align__(16) float Al[32][128];
  const int tid = threadIdx.x;

  {  // each weight: 2048 float4
    const float4* Wm4 = (const float4*)Wmu;
    const float4* Ws4 = (const float4*)Wstd;
#pragma unroll
    for (int i = 0; i < 8; ++i) {
      int idx = tid + i * 256;
      int k = idx >> 4;
      int c4 = idx & 15;
      *(float4*)&Wl[k][c4 * 4] = Wm4[idx];
      *(float4*)&Wl[k][64 + c4 * 4] = Ws4[idx];
    }
  }
  const int row0 = blockIdx.x * 32;
  {
    const float4* A4 = (const float4*)(A + (size_t)row0 * D);
    float4* Al4 = (float4*)&Al[0][0];
#pragma unroll
    for (int i = 0; i < 4; ++i) {
      int idx = tid + i * 256;
      int r = idx >> 5;
      float4 v = make_float4(0.f, 0.f, 0.f, 0.f);
      if (row0 + r < N) v = A4[idx];
      Al4[idx] = v;
    }
  }
  __syncthreads();

  const int c0 = (tid & 31) * 4;
  const int r0 = (tid >> 5) * 4;
  float acc[4][4] = {};
  for (int k4 = 0; k4 < 32; ++k4) {
    float4 a[4];
#pragma unroll
    for (int r = 0; r < 4; ++r) a[r] = *(const float4*)&Al[r0 + r][k4 * 4];
    float4 w[4];
#pragma unroll
    for (int kk = 0; kk < 4; ++kk) w[kk] = *(const float4*)&Wl[k4 * 4 + kk][c0];
#pragma unroll
    for (int r = 0; r < 4; ++r) {
      float av0 = a[r].x, av1 = a[r].y, av2 = a[r].z, av3 = a[r].w;
#pragma unroll
      for (int cc = 0; cc < 4; ++cc) {
        float wv0 = (&w[0].x)[cc], wv1 = (&w[1].x)[cc], wv2 = (&w[2].x)[cc], wv3 = (&w[3].x)[cc];
        float v = acc[r][cc];
        v = fmaf(av0, wv0, v);
        v = fmaf(av1, wv1, v);
        v = fmaf(av2, wv2, v);
        v = fmaf(av3, wv3, v);
        acc[r][cc] = v;
      }
    }
  }
  const bool is_mu = (c0 < DO);
  const int cc0 = is_mu ? c0 : (c0 - DO);
  const float* bsel = is_mu ? bmu : bstd;
  float4 b = *(const float4*)&bsel[cc0];
  float* base = is_mu ? out : (out + (size_t)N * DO);
#pragma unroll
  for (int r = 0; r < 4; ++r) {
    int row = row0 + r0 + r;
    if (row < N) {
      float4 v;
      v.x = acc[r][0] + b.x; v.y = acc[r][1] + b.y;
      v.z = acc[r][2] + b.z; v.w = acc[r][3] + b.w;
      *(float4*)&base[(size_t)row * DO + cc0] = v;
    }
  }
}

// ---------------- launcher ----------------

extern "C" void kernel_launch(void* const* d_in, const int* in_sizes, int n_in,
                              void* d_out, int out_size, void* d_ws, size_t ws_size,
                              hipStream_t stream) {
  const float* x    = (const float*)d_in[0];
  const int*   ei   = (const int*)d_in[1];     // [2, E] int32
  const float* ew   = (const float*)d_in[2];
  const float* W1   = (const float*)d_in[3];
  const float* b1   = (const float*)d_in[4];
  const float* W2   = (const float*)d_in[5];
  const float* b2   = (const float*)d_in[6];
  const float* Wmu  = (const float*)d_in[7];
  const float* bmu  = (const float*)d_in[8];
  const float* Wstd = (const float*)d_in[9];
  const float* bstd = (const float*)d_in[10];
  float* out = (float*)d_out;

  const int* srcI = ei;
  const int* dstI = ei + E;

  char* p = (char*)d_ws;
  float* dinv    = (float*)p;  p += (size_t)N * 4;
  int*   rowptr  = (int*)p;    p += (size_t)(N + 1) * 4;
  int*   cursor  = (int*)p;    p += (size_t)N * 4;
  int*   partial = (int*)p;    p += (size_t)256 * 4;
  int*   csr_src = (int*)p;    p += (size_t)E * 4;
  float* csr_w   = (float*)p;  p += (size_t)E * 4;
  float* buf0    = (float*)p;  p += (size_t)N * D * 4;   // aggregation result
  float* buf1    = (float*)p;                            // post-GEMM h

  dim3 blk(256);
  const int gN   = (N + 255) / 256;
  const int gE   = (E + 255) / 256;
  const int gAgg = (N + 3) / 4;
  const int gGemm = (N + 31) / 32;   // 1563

  // CSR + norm precompute (once per call)
  k_init<<<gN, blk, 0, stream>>>(dinv, rowptr);
  k_hist<<<gE, blk, 0, stream>>>(dstI, ew, dinv, rowptr);
  k_finalize_dinv<<<gN, blk, 0, stream>>>(dinv);
  k_scan1<<<NB, blk, 0, stream>>>(rowptr, partial);
  k_scan2<<<1, blk, 0, stream>>>(partial);
  k_scan3<<<NB, blk, 0, stream>>>(rowptr, partial, rowptr, cursor);
  k_build_csr<<<gE, blk, 0, stream>>>(srcI, dstI, ew, dinv, cursor, csr_src, csr_w);

  // layer 1: h1 = relu(A(x) @ W1 + b1)
  k_aggregate<<<gAgg, blk, 0, stream>>>(x, rowptr, csr_src, csr_w, dinv, buf0);
  k_gemm_bias<true><<<gGemm, blk, 0, stream>>>(buf0, W1, b1, buf1);

  // layer 2: h2 = relu(A(h1) @ W2 + b2)
  k_aggregate<<<gAgg, blk, 0, stream>>>(buf1, rowptr, csr_src, csr_w, dinv, buf0);
  k_gemm_bias<true><<<gGemm, blk, 0, stream>>>(buf0, W2, b2, buf1);

  // heads: one shared aggregation, two output projections
  k_aggregate<<<gAgg, blk, 0, stream>>>(buf1, rowptr, csr_src, csr_w, dinv, buf0);
  k_gemm_dual<<<gGemm, blk, 0, stream>>>(buf0, Wmu, Wstd, bmu, bstd, out);
}

// Round 4
// 368.613 us; speedup vs baseline: 11.5132x; 1.1968x over previous
//
#include <hip/hip_runtime.h>
#include <math.h>

static constexpr int N = 50000;
static constexpr int E = 800000;
static constexpr int D = 128;      // D_IN = D_HID
static constexpr int DO = 64;      // D_OUT
static constexpr int NB = (N + 255) / 256;   // 196 scan blocks

// ---------------- degree+count histogram (packed u64 atomic) ----------------
// packed[i] = (cnt << 48) | sum_fix48(ew * 2^31)

__global__ __launch_bounds__(256) void k_init(unsigned long long* __restrict__ packed) {
  int i = blockIdx.x * 256 + threadIdx.x;
  if (i < N) packed[i] = 0ULL;
}

__global__ __launch_bounds__(256) void k_hist(const int* __restrict__ dst,
                                              const float* __restrict__ ew,
                                              unsigned long long* __restrict__ packed) {
  int e = blockIdx.x * 256 + threadIdx.x;
  if (e < E) {
    unsigned wfix = (unsigned)(ew[e] * 2147483648.0f + 0.5f);
    unsigned long long inc = (1ULL << 48) | (unsigned long long)wfix;
    __hip_atomic_fetch_add(&packed[dst[e]], inc, __ATOMIC_RELAXED, __HIP_MEMORY_SCOPE_AGENT);
  }
}

// extract dinv and cnt (cnt goes into `cursor`, which scan3 later overwrites)
__global__ __launch_bounds__(256) void k_finalize(const unsigned long long* __restrict__ packed,
                                                  float* __restrict__ dinv,
                                                  int* __restrict__ cnt) {
  int i = blockIdx.x * 256 + threadIdx.x;
  if (i < N) {
    unsigned long long v = packed[i];
    cnt[i] = (int)(v >> 48);
    float deg = 1.0f + (float)((double)(v & 0x0000FFFFFFFFFFFFULL) * (1.0 / 2147483648.0));
    dinv[i] = 1.0f / sqrtf(deg);
  }
}

// hierarchical scan: S1 block sums -> S2 scan partials -> S3 local scan + offset
__global__ __launch_bounds__(256) void k_scan1(const int* __restrict__ cnt,
                                               int* __restrict__ partial) {
  __shared__ int sm[256];
  int i = blockIdx.x * 256 + threadIdx.x;
  int t = threadIdx.x;
  sm[t] = (i < N) ? cnt[i] : 0;
  __syncthreads();
#pragma unroll
  for (int off = 128; off > 0; off >>= 1) {
    if (t < off) sm[t] += sm[t + off];
    __syncthreads();
  }
  if (t == 0) partial[blockIdx.x] = sm[0];
}

__global__ __launch_bounds__(256) void k_scan2(int* __restrict__ partial) {
  __shared__ int sm[256];
  int t = threadIdx.x;
  int v = (t < NB) ? partial[t] : 0;
  sm[t] = v;
  __syncthreads();
#pragma unroll
  for (int off = 1; off < 256; off <<= 1) {
    int u = (t >= off) ? sm[t - off] : 0;
    __syncthreads();
    sm[t] += u;
    __syncthreads();
  }
  if (t < NB) partial[t] = sm[t] - v;   // exclusive block offsets
}

// cnt_in aliases `cursor`; each thread re-writes cursor[i] after reading it
__global__ __launch_bounds__(256) void k_scan3(const int* __restrict__ cnt_in,
                                               const int* __restrict__ partial,
                                               int* __restrict__ rowptr,
                                               int* __restrict__ cursor) {
  __shared__ int sm[256];
  int i = blockIdx.x * 256 + threadIdx.x;
  int t = threadIdx.x;
  int v = (i < N) ? cnt_in[i] : 0;
  sm[t] = v;
  __syncthreads();
#pragma unroll
  for (int off = 1; off < 256; off <<= 1) {
    int u = (t >= off) ? sm[t - off] : 0;
    __syncthreads();
    sm[t] += u;
    __syncthreads();
  }
  int excl = sm[t] - v + partial[blockIdx.x];
  if (i < N) { rowptr[i] = excl; cursor[i] = excl; }
  if (i == N) rowptr[N] = E;
}

// scatter edges into CSR order (packed int2: src, float_bits(norm))
__global__ __launch_bounds__(256) void k_build_csr(const int* __restrict__ src,
                                                   const int* __restrict__ dst,
                                                   const float* __restrict__ ew,
                                                   const float* __restrict__ dinv,
                                                   int* __restrict__ cursor,
                                                   int2* __restrict__ csr) {
  int e = blockIdx.x * 256 + threadIdx.x;
  if (e >= E) return;
  int s = src[e], d = dst[e];
  float w = dinv[s] * ew[e] * dinv[d];
  int pos = __hip_atomic_fetch_add(&cursor[d], 1, __ATOMIC_RELAXED, __HIP_MEMORY_SCOPE_AGENT);
  csr[pos] = make_int2(s, __float_as_int(w));
}

// ---------------- aggregation: out[i] = sum_{e->i} h[src]*w + h[i]*dinv[i]^2 ----------------
// one 64-lane wave per node; lane owns float2 of the 128-dim row; 8x edge unroll
__global__ __launch_bounds__(256) void k_aggregate(const float* __restrict__ h,
                                                   const int* __restrict__ rowptr,
                                                   const int2* __restrict__ csr,
                                                   const float* __restrict__ dinv,
                                                   float* __restrict__ out) {
  int node = blockIdx.x * 4 + (threadIdx.x >> 6);
  if (node >= N) return;
  int lane = threadIdx.x & 63;
  const float* hp = h + (size_t)lane * 2;

  float s = dinv[node];
  float s2 = s * s;
  float2 hv = *(const float2*)(hp + (size_t)node * D);
  float ax = hv.x * s2, ay = hv.y * s2;

  int e = rowptr[node];
  int end = rowptr[node + 1];

  // peel to even e so int4 (16B) loads on csr are aligned
  if ((e & 1) && e < end) {
    int2 pe = csr[e];
    float w = __int_as_float(pe.y);
    float2 v = *(const float2*)(hp + (size_t)pe.x * D);
    ax = fmaf(v.x, w, ax); ay = fmaf(v.y, w, ay);
    ++e;
  }
  for (; e + 8 <= end; e += 8) {
    int4 p0 = *(const int4*)(csr + e + 0);
    int4 p1 = *(const int4*)(csr + e + 2);
    int4 p2 = *(const int4*)(csr + e + 4);
    int4 p3 = *(const int4*)(csr + e + 6);
    float2 v0 = *(const float2*)(hp + (size_t)p0.x * D);
    float2 v1 = *(const float2*)(hp + (size_t)p0.z * D);
    float2 v2 = *(const float2*)(hp + (size_t)p1.x * D);
    float2 v3 = *(const float2*)(hp + (size_t)p1.z * D);
    float2 v4 = *(const float2*)(hp + (size_t)p2.x * D);
    float2 v5 = *(const float2*)(hp + (size_t)p2.z * D);
    float2 v6 = *(const float2*)(hp + (size_t)p3.x * D);
    float2 v7 = *(const float2*)(hp + (size_t)p3.z * D);
    float w0 = __int_as_float(p0.y), w1 = __int_as_float(p0.w);
    float w2 = __int_as_float(p1.y), w3 = __int_as_float(p1.w);
    float w4 = __int_as_float(p2.y), w5 = __int_as_float(p2.w);
    float w6 = __int_as_float(p3.y), w7 = __int_as_float(p3.w);
    ax = fmaf(v0.x, w0, ax); ay = fmaf(v0.y, w0, ay);
    ax = fmaf(v1.x, w1, ax); ay = fmaf(v1.y, w1, ay);
    ax = fmaf(v2.x, w2, ax); ay = fmaf(v2.y, w2, ay);
    ax = fmaf(v3.x, w3, ax); ay = fmaf(v3.y, w3, ay);
    ax = fmaf(v4.x, w4, ax); ay = fmaf(v4.y, w4, ay);
    ax = fmaf(v5.x, w5, ax); ay = fmaf(v5.y, w5, ay);
    ax = fmaf(v6.x, w6, ax); ay = fmaf(v6.y, w6, ay);
    ax = fmaf(v7.x, w7, ax); ay = fmaf(v7.y, w7, ay);
  }
  for (; e + 2 <= end; e += 2) {
    int4 p0 = *(const int4*)(csr + e);
    float2 v0 = *(const float2*)(hp + (size_t)p0.x * D);
    float2 v1 = *(const float2*)(hp + (size_t)p0.z * D);
    float w0 = __int_as_float(p0.y), w1 = __int_as_float(p0.w);
    ax = fmaf(v0.x, w0, ax); ay = fmaf(v0.y, w0, ay);
    ax = fmaf(v1.x, w1, ax); ay = fmaf(v1.y, w1, ay);
  }
  if (e < end) {
    int2 pe = csr[e];
    float w = __int_as_float(pe.y);
    float2 v = *(const float2*)(hp + (size_t)pe.x * D);
    ax = fmaf(v.x, w, ax); ay = fmaf(v.y, w, ay);
  }
  float2 r; r.x = ax; r.y = ay;
  *(float2*)(out + (size_t)node * D + lane * 2) = r;
}

// ---------------- GEMM: out[N,128] = A[N,128] @ W[128,128] + bias (opt relu) ----------------

template <bool RELU>
__global__ __launch_bounds__(256) void k_gemm_bias(const float* __restrict__ A,
                                                   const float* __restrict__ W,
                                                   const float* __restrict__ bias,
                                                   float* __restrict__ out) {
  __shared__ __align__(16) float Wl[128][128];
  __shared__ __align__(16) float Al[32][128];
  const int tid = threadIdx.x;

  {
    const float4* W4 = (const float4*)W;
    float4* Wl4 = (float4*)&Wl[0][0];
#pragma unroll
    for (int i = 0; i < 16; ++i) Wl4[tid + i * 256] = W4[tid + i * 256];
  }
  const int row0 = blockIdx.x * 32;
  {
    const float4* A4 = (const float4*)(A + (size_t)row0 * D);
    float4* Al4 = (float4*)&Al[0][0];
#pragma unroll
    for (int i = 0; i < 4; ++i) {
      int idx = tid + i * 256;
      int r = idx >> 5;
      float4 v = make_float4(0.f, 0.f, 0.f, 0.f);
      if (row0 + r < N) v = A4[idx];
      Al4[idx] = v;
    }
  }
  __syncthreads();

  const int c0 = (tid & 31) * 4;
  const int r0 = (tid >> 5) * 4;
  float acc[4][4] = {};
  for (int k4 = 0; k4 < 32; ++k4) {
    float4 a[4];
#pragma unroll
    for (int r = 0; r < 4; ++r) a[r] = *(const float4*)&Al[r0 + r][k4 * 4];
    float4 w[4];
#pragma unroll
    for (int kk = 0; kk < 4; ++kk) w[kk] = *(const float4*)&Wl[k4 * 4 + kk][c0];
#pragma unroll
    for (int r = 0; r < 4; ++r) {
      float av0 = a[r].x, av1 = a[r].y, av2 = a[r].z, av3 = a[r].w;
#pragma unroll
      for (int cc = 0; cc < 4; ++cc) {
        float wv0 = (&w[0].x)[cc], wv1 = (&w[1].x)[cc], wv2 = (&w[2].x)[cc], wv3 = (&w[3].x)[cc];
        float v = acc[r][cc];
        v = fmaf(av0, wv0, v);
        v = fmaf(av1, wv1, v);
        v = fmaf(av2, wv2, v);
        v = fmaf(av3, wv3, v);
        acc[r][cc] = v;
      }
    }
  }
  float4 b = *(const float4*)&bias[c0];
#pragma unroll
  for (int r = 0; r < 4; ++r) {
    int row = row0 + r0 + r;
    if (row < N) {
      float4 v;
      v.x = acc[r][0] + b.x; v.y = acc[r][1] + b.y;
      v.z = acc[r][2] + b.z; v.w = acc[r][3] + b.w;
      if (RELU) {
        v.x = fmaxf(v.x, 0.f); v.y = fmaxf(v.y, 0.f);
        v.z = fmaxf(v.z, 0.f); v.w = fmaxf(v.w, 0.f);
      }
      *(float4*)&out[(size_t)row * D + c0] = v;
    }
  }
}

// heads: cols 0-63 -> mu = A@Wmu+bmu, cols 64-127 -> std = A@Wstd+bstd
__global__ __launch_bounds__(256) void k_gemm_dual(const float* __restrict__ A,
                                                   const float* __restrict__ Wmu,
                                                   const float* __restrict__ Wstd,
                                                   const float* __restrict__ bmu,
                                                   const float* __restrict__ bstd,
                                                   float* __restrict__ out) {
  __shared__ __align__(16) float Wl[128][128];
  __shared__ __align__(16) float Al[32][128];
  const int tid = threadIdx.x;

  {
    const float4* Wm4 = (const float4*)Wmu;
    const float4* Ws4 = (const float4*)Wstd;
#pragma unroll
    for (int i = 0; i < 8; ++i) {
      int idx = tid + i * 256;
      int k = idx >> 4;
      int c4 = idx & 15;
      *(float4*)&Wl[k][c4 * 4] = Wm4[idx];
      *(float4*)&Wl[k][64 + c4 * 4] = Ws4[idx];
    }
  }
  const int row0 = blockIdx.x * 32;
  {
    const float4* A4 = (const float4*)(A + (size_t)row0 * D);
    float4* Al4 = (float4*)&Al[0][0];
#pragma unroll
    for (int i = 0; i < 4; ++i) {
      int idx = tid + i * 256;
      int r = idx >> 5;
      float4 v = make_float4(0.f, 0.f, 0.f, 0.f);
      if (row0 + r < N) v = A4[idx];
      Al4[idx] = v;
    }
  }
  __syncthreads();

  const int c0 = (tid & 31) * 4;
  const int r0 = (tid >> 5) * 4;
  float acc[4][4] = {};
  for (int k4 = 0; k4 < 32; ++k4) {
    float4 a[4];
#pragma unroll
    for (int r = 0; r < 4; ++r) a[r] = *(const float4*)&Al[r0 + r][k4 * 4];
    float4 w[4];
#pragma unroll
    for (int kk = 0; kk < 4; ++kk) w[kk] = *(const float4*)&Wl[k4 * 4 + kk][c0];
#pragma unroll
    for (int r = 0; r < 4; ++r) {
      float av0 = a[r].x, av1 = a[r].y, av2 = a[r].z, av3 = a[r].w;
#pragma unroll
      for (int cc = 0; cc < 4; ++cc) {
        float wv0 = (&w[0].x)[cc], wv1 = (&w[1].x)[cc], wv2 = (&w[2].x)[cc], wv3 = (&w[3].x)[cc];
        float v = acc[r][cc];
        v = fmaf(av0, wv0, v);
        v = fmaf(av1, wv1, v);
        v = fmaf(av2, wv2, v);
        v = fmaf(av3, wv3, v);
        acc[r][cc] = v;
      }
    }
  }
  const bool is_mu = (c0 < DO);
  const int cc0 = is_mu ? c0 : (c0 - DO);
  const float* bsel = is_mu ? bmu : bstd;
  float4 b = *(const float4*)&bsel[cc0];
  float* base = is_mu ? out : (out + (size_t)N * DO);
#pragma unroll
  for (int r = 0; r < 4; ++r) {
    int row = row0 + r0 + r;
    if (row < N) {
      float4 v;
      v.x = acc[r][0] + b.x; v.y = acc[r][1] + b.y;
      v.z = acc[r][2] + b.z; v.w = acc[r][3] + b.w;
      *(float4*)&base[(size_t)row * DO + cc0] = v;
    }
  }
}

// ---------------- launcher ----------------

static inline char* align256(char* p) {
  return (char*)(((uintptr_t)p + 255) & ~(uintptr_t)255);
}

extern "C" void kernel_launch(void* const* d_in, const int* in_sizes, int n_in,
                              void* d_out, int out_size, void* d_ws, size_t ws_size,
                              hipStream_t stream) {
  const float* x    = (const float*)d_in[0];
  const int*   ei   = (const int*)d_in[1];     // [2, E] int32
  const float* ew   = (const float*)d_in[2];
  const float* W1   = (const float*)d_in[3];
  const float* b1   = (const float*)d_in[4];
  const float* W2   = (const float*)d_in[5];
  const float* b2   = (const float*)d_in[6];
  const float* Wmu  = (const float*)d_in[7];
  const float* bmu  = (const float*)d_in[8];
  const float* Wstd = (const float*)d_in[9];
  const float* bstd = (const float*)d_in[10];
  float* out = (float*)d_out;

  const int* srcI = ei;
  const int* dstI = ei + E;

  char* p = (char*)d_ws;
  float* dinv    = (float*)p;            p = align256(p + (size_t)N * 4);
  int*   rowptr  = (int*)p;              p = align256(p + (size_t)(N + 1) * 4);
  int*   cursor  = (int*)p;              p = align256(p + (size_t)N * 4);
  int*   partial = (int*)p;              p = align256(p + (size_t)256 * 4);
  int2*  csr     = (int2*)p;             p = align256(p + (size_t)E * 8);
  float* buf0    = (float*)p;            p = align256(p + (size_t)N * D * 4);
  float* buf1    = (float*)p;
  // packed u64 histogram aliases buf0 (consumed before buf0 is first written)
  unsigned long long* packed = (unsigned long long*)buf0;

  dim3 blk(256);
  const int gN   = (N + 255) / 256;
  const int gN1  = (N + 256) / 256;      // covers i == N in scan3
  const int gE   = (E + 255) / 256;
  const int gAgg = (N + 3) / 4;
  const int gGemm = (N + 31) / 32;

  // CSR + norm precompute (once per call)
  k_init<<<gN, blk, 0, stream>>>(packed);
  k_hist<<<gE, blk, 0, stream>>>(dstI, ew, packed);
  k_finalize<<<gN, blk, 0, stream>>>(packed, dinv, cursor);   // cnt -> cursor
  k_scan1<<<NB, blk, 0, stream>>>(cursor, partial);
  k_scan2<<<1, blk, 0, stream>>>(partial);
  k_scan3<<<gN1, blk, 0, stream>>>(cursor, partial, rowptr, cursor);
  k_build_csr<<<gE, blk, 0, stream>>>(srcI, dstI, ew, dinv, cursor, csr);

  // layer 1: h1 = relu(A(x) @ W1 + b1)
  k_aggregate<<<gAgg, blk, 0, stream>>>(x, rowptr, csr, dinv, buf0);
  k_gemm_bias<true><<<gGemm, blk, 0, stream>>>(buf0, W1, b1, buf1);

  // layer 2: h2 = relu(A(h1) @ W2 + b2)
  k_aggregate<<<gAgg, blk, 0, stream>>>(buf1, rowptr, csr, dinv, buf0);
  k_gemm_bias<true><<<gGemm, blk, 0, stream>>>(buf0, W2, b2, buf1);

  // heads: one shared aggregation, two output projections
  k_aggregate<<<gAgg, blk, 0, stream>>>(buf1, rowptr, csr, dinv, buf0);
  k_gemm_dual<<<gGemm, blk, 0, stream>>>(buf0, Wmu, Wstd, bmu, bstd, out);
}